// Round 7
// baseline (459.894 us; speedup 1.0000x reference)
//
#include <hip/hip_runtime.h>

#define NN 100000
#define EE 1600000
#define DIM 128
#define NBUCK ((NN + 255) >> 8)   // 391 buckets of 256 nodes
#define B1 128                    // bucket-pass blocks
#define CH ((EE + B1 - 1) / B1)   // 12500 edges per block

typedef unsigned int u32;
typedef __attribute__((ext_vector_type(8))) short bf16x8;
typedef __attribute__((ext_vector_type(4))) float f32x4;

union U4 { uint4 u; bf16x8 h; };

__device__ __forceinline__ float lof(u32 u) { return __uint_as_float(u << 16); }
__device__ __forceinline__ float hif(u32 u) { return __uint_as_float(u & 0xffff0000u); }
__device__ __forceinline__ u32 pack_bf2(float a, float b) {
  u32 ua = __float_as_uint(a), ub = __float_as_uint(b);
  ua = (ua + 0x7fffu + ((ua >> 16) & 1u)) >> 16;
  ub = (ub + 0x7fffu + ((ub >> 16) & 1u)) & 0xffff0000u;
  return ua | ub;
}

// ---------------- pass A: per-block bucket histogram ----------------
__global__ __launch_bounds__(256) void k_hist(const int* __restrict__ dst,
                                              int* __restrict__ hist_t) {
  __shared__ int h[NBUCK];
  for (int i = threadIdx.x; i < NBUCK; i += 256) h[i] = 0;
  __syncthreads();
  int e0 = blockIdx.x * CH;
  int e1 = e0 + CH < EE ? e0 + CH : EE;
  for (int e = e0 + threadIdx.x; e < e1; e += 256)
    atomicAdd(&h[dst[e] >> 8], 1);
  __syncthreads();
  for (int i = threadIdx.x; i < NBUCK; i += 256)
    hist_t[i * B1 + blockIdx.x] = h[i];
}

// ---------------- pass B: per-bucket scan over blocks ----------------
__global__ __launch_bounds__(B1) void k_boff(const int* __restrict__ hist_t,
                                             int* __restrict__ blockoff,
                                             int* __restrict__ btot) {
  __shared__ int ps[B1];
  int j = blockIdx.x, t = threadIdx.x;
  int v = hist_t[j * B1 + t];
  ps[t] = v;
  __syncthreads();
  #pragma unroll
  for (int off = 1; off < B1; off <<= 1) {
    int u = (t >= off) ? ps[t - off] : 0;
    __syncthreads();
    ps[t] += u;
    __syncthreads();
  }
  blockoff[j * B1 + t] = ps[t] - v;
  if (t == B1 - 1) btot[j] = ps[t];
}

// ---------------- pass B2: scan bucket totals -> bbase ----------------
__global__ __launch_bounds__(512) void k_bbase(const int* __restrict__ btot,
                                               int* __restrict__ bbase) {
  __shared__ int ps[512];
  int t = threadIdx.x;
  int v = (t < NBUCK) ? btot[t] : 0;
  ps[t] = v;
  __syncthreads();
  #pragma unroll
  for (int off = 1; off < 512; off <<= 1) {
    int u = (t >= off) ? ps[t - off] : 0;
    __syncthreads();
    ps[t] += u;
    __syncthreads();
  }
  if (t < NBUCK) bbase[t] = ps[t] - v;
  if (t == 0) bbase[NBUCK] = EE;
}

// ---------------- pass C: scatter (dst,src) pairs into bucket regions ----------------
__global__ __launch_bounds__(256) void k_bucket(const int* __restrict__ src,
                                                const int* __restrict__ dst,
                                                const int* __restrict__ bbase,
                                                const int* __restrict__ blockoff,
                                                int2* __restrict__ epair) {
  __shared__ int cnt[NBUCK];
  for (int i = threadIdx.x; i < NBUCK; i += 256) cnt[i] = 0;
  __syncthreads();
  int e0 = blockIdx.x * CH;
  int e1 = e0 + CH < EE ? e0 + CH : EE;
  for (int e = e0 + threadIdx.x; e < e1; e += 256) {
    int d = dst[e], s = src[e];
    int j = d >> 8;
    int loc = atomicAdd(&cnt[j], 1);
    epair[bbase[j] + blockoff[j * B1 + blockIdx.x] + loc] = make_int2(d, s);
  }
}

// ---------------- pass D: per-bucket deg/ds/rp + fine scatter -> esrc ----------------
__global__ __launch_bounds__(256) void k_fine(const int2* __restrict__ epair,
                                              const int* __restrict__ bbase,
                                              int* __restrict__ rp,
                                              float* __restrict__ ds,
                                              int* __restrict__ esrc) {
  __shared__ int cntA[256], cntB[256], rpl[256], ps[256];
  int j = blockIdx.x, t = threadIdx.x;
  int node0 = j << 8;
  int e0 = bbase[j], e1 = bbase[j + 1];
  cntA[t] = 0;
  cntB[t] = 0;
  __syncthreads();
  for (int e = e0 + t; e < e1; e += 256)
    atomicAdd(&cntA[epair[e].x & 255], 1);
  __syncthreads();
  int deg = cntA[t];
  ps[t] = deg;
  __syncthreads();
  #pragma unroll
  for (int off = 1; off < 256; off <<= 1) {
    int u = (t >= off) ? ps[t - off] : 0;
    __syncthreads();
    ps[t] += u;
    __syncthreads();
  }
  rpl[t] = e0 + ps[t] - deg;
  __syncthreads();
  int node = node0 + t;
  if (node < NN) {
    rp[node] = rpl[t];
    ds[node] = rsqrtf(fmaxf((float)deg, 1.0f));
  }
  if (j == 0 && t == 0) rp[NN] = EE;
  for (int e = e0 + t; e < e1; e += 256) {
    int2 pr = epair[e];
    int d = pr.x & 255;
    int pos = rpl[d] + atomicAdd(&cntB[d], 1);
    esrc[pos] = pr.y;
  }
}

// ---------------- prep: X0b/Y0 tables + fused Wf (fragment-major bf16 W) ----
__global__ void k_prep(const float* __restrict__ feature, const float* __restrict__ ds,
                       u32* __restrict__ X0b, u32* __restrict__ Y0,
                       const float* __restrict__ W, u32* __restrict__ Wf) {
  int i = blockIdx.x * blockDim.x + threadIdx.x;
  if (i < 96 * 256) {
    // Wf u32 index = ((phase*4+ks)*8+nj)*256 + lane*4 + j
    int fi = i >> 8;
    int lane = (i >> 2) & 63;
    int jj = i & 3;
    int phase = fi >> 5, ks = (fi >> 3) & 3, nj = fi & 7;
    int g = lane >> 4, l15 = lane & 15;
    int nn = nj * 16 + l15;
    int ku = phase * 64 + ks * 16 + g * 4 + jj;
    int k = ku * 2;
    float w0 = W[(size_t)k * 128 + nn];
    float w1 = W[(size_t)(k + 1) * 128 + nn];
    Wf[i] = pack_bf2(w0, w1);
  }
  const int total = NN * 32;  // uint2 count (4 dims each)
  int st = gridDim.x * blockDim.x;
  for (int j = i; j < total; j += st) {
    int n = j >> 5;
    float4 f = *(const float4*)(feature + (size_t)n * DIM + (j & 31) * 4);
    float dsn = ds[n];
    ((uint2*)X0b)[j] = make_uint2(pack_bf2(f.x, f.y), pack_bf2(f.z, f.w));
    ((uint2*)Y0)[j] = make_uint2(pack_bf2(f.x * dsn, f.y * dsn),
                                 pack_bf2(f.z * dsn, f.w * dsn));
  }
}

// ---------------- prop1: X1 = -ds[n]*sum Y0[s]; write X1b, Y1 = X1*ds[n] ----------------
// 8 independent gather chains; tails via wave-uniform guards (no wasted loads).
__global__ __launch_bounds__(256) void k_prop1(const u32* __restrict__ Y0,
                                               const float* __restrict__ ds,
                                               const int* __restrict__ rp,
                                               const int* __restrict__ esrc,
                                               u32* __restrict__ X1b,
                                               u32* __restrict__ Y1) {
  int n = blockIdx.x * 4 + (threadIdx.x >> 6);
  int l = threadIdx.x & 63;
  int beg = rp[n], end = rp[n + 1];
  float ax[8], ay[8];
  #pragma unroll
  for (int i = 0; i < 8; ++i) { ax[i] = 0.f; ay[i] = 0.f; }
  for (int p = beg; p < end; p += 8) {
    #pragma unroll
    for (int i = 0; i < 8; ++i) {
      int q = p + i;
      if (q < end) {
        u32 u = Y0[(size_t)esrc[q] * 64 + l];
        ax[i] += lof(u); ay[i] += hif(u);
      }
    }
  }
  float sx = ((ax[0] + ax[4]) + (ax[2] + ax[6])) + ((ax[1] + ax[5]) + (ax[3] + ax[7]));
  float sy = ((ay[0] + ay[4]) + (ay[2] + ay[6])) + ((ay[1] + ay[5]) + (ay[3] + ay[7]));
  float dsn = ds[n];
  float x = -dsn * sx;
  float y = -dsn * sy;
  X1b[(size_t)n * 64 + l] = pack_bf2(x, y);
  Y1[(size_t)n * 64 + l] = pack_bf2(x * dsn, y * dsn);
}

// ---------------- prop2: X2 = -2*ds[n]*sum Y1[s] - X0 ----------------
__global__ __launch_bounds__(256) void k_prop2(const u32* __restrict__ Y1,
                                               const u32* __restrict__ X0b,
                                               const float* __restrict__ ds,
                                               const int* __restrict__ rp,
                                               const int* __restrict__ esrc,
                                               u32* __restrict__ X2b) {
  int n = blockIdx.x * 4 + (threadIdx.x >> 6);
  int l = threadIdx.x & 63;
  int beg = rp[n], end = rp[n + 1];
  float ax[8], ay[8];
  #pragma unroll
  for (int i = 0; i < 8; ++i) { ax[i] = 0.f; ay[i] = 0.f; }
  for (int p = beg; p < end; p += 8) {
    #pragma unroll
    for (int i = 0; i < 8; ++i) {
      int q = p + i;
      if (q < end) {
        u32 u = Y1[(size_t)esrc[q] * 64 + l];
        ax[i] += lof(u); ay[i] += hif(u);
      }
    }
  }
  float sx = ((ax[0] + ax[4]) + (ax[2] + ax[6])) + ((ax[1] + ax[5]) + (ax[3] + ax[7]));
  float sy = ((ay[0] + ay[4]) + (ay[2] + ay[6])) + ((ay[1] + ay[5]) + (ay[3] + ay[7]));
  float dsn = ds[n];
  u32 u0 = X0b[(size_t)n * 64 + l];
  float x = -2.0f * dsn * sx - lof(u0);
  float y = -2.0f * dsn * sy - hif(u0);
  X2b[(size_t)n * 64 + l] = pack_bf2(x, y);
}

// ---------------- MFMA GEMM with LDS-staged fragment-major W ----------------
__global__ __launch_bounds__(1024) void k_gemm(const u32* __restrict__ X0b,
                                               const u32* __restrict__ X1b,
                                               const u32* __restrict__ X2b,
                                               const u32* __restrict__ Wf,
                                               const float* __restrict__ bias,
                                               const float* __restrict__ snorm,
                                               float* __restrict__ out,
                                               float* __restrict__ gsum,
                                               float* __restrict__ gsq) {
  __shared__ u32 wlds[24576];   // 96 KB
  __shared__ float ls[256];
  int tid = threadIdx.x;
  #pragma unroll
  for (int l = 0; l < 6; ++l) {
    int it = tid + l * 1024;
    ((uint4*)wlds)[it] = ((const uint4*)Wf)[it];
  }
  int wid = tid >> 6, lane = tid & 63;
  int l15 = lane & 15, g = lane >> 4;
  int row0 = blockIdx.x * 512 + wid * 32;
  bool active = (row0 + 32) <= NN;
  if (!active) row0 = 0;

  size_t rb0 = (size_t)(row0 + l15) * 64 + g * 4;
  size_t rb1 = rb0 + (size_t)16 * 64;

  f32x4 acc[2][8];
  #pragma unroll
  for (int mi = 0; mi < 2; ++mi)
    #pragma unroll
    for (int nj = 0; nj < 8; ++nj) acc[mi][nj] = (f32x4){0.f, 0.f, 0.f, 0.f};

  __syncthreads();

  const u32* tabs[3] = {X0b, X1b, X2b};
  #pragma unroll
  for (int phase = 0; phase < 3; ++phase) {
    const u32* A = tabs[phase];
    #pragma unroll
    for (int ks = 0; ks < 4; ++ks) {
      U4 a0, a1;
      a0.u = *(const uint4*)(A + rb0 + ks * 16);
      a1.u = *(const uint4*)(A + rb1 + ks * 16);
      #pragma unroll
      for (int nj = 0; nj < 8; ++nj) {
        U4 b;
        b.u = ((const uint4*)wlds)[((phase * 4 + ks) * 8 + nj) * 64 + lane];
        acc[0][nj] = __builtin_amdgcn_mfma_f32_16x16x32_bf16(a0.h, b.h, acc[0][nj], 0, 0, 0);
        acc[1][nj] = __builtin_amdgcn_mfma_f32_16x16x32_bf16(a1.h, b.h, acc[1][nj], 0, 0, 0);
      }
    }
  }

  float cs[8], cq[8];
  #pragma unroll
  for (int nj = 0; nj < 8; ++nj) { cs[nj] = 0.f; cq[nj] = 0.f; }
  if (active) {
    float bs[8];
    #pragma unroll
    for (int nj = 0; nj < 8; ++nj) bs[nj] = bias[nj * 16 + l15];
    #pragma unroll
    for (int mi = 0; mi < 2; ++mi) {
      #pragma unroll
      for (int r = 0; r < 4; ++r) {
        int row = row0 + mi * 16 + g * 4 + r;
        float sn = snorm[row];
        #pragma unroll
        for (int nj = 0; nj < 8; ++nj) {
          float h = (acc[mi][nj][r] + bs[nj]) * sn;
          out[(size_t)row * DIM + nj * 16 + l15] = h;
          cs[nj] += h;
          cq[nj] += h * h;
        }
      }
    }
  }
  if (tid < 256) ls[tid] = 0.f;
  __syncthreads();
  if (active) {
    #pragma unroll
    for (int nj = 0; nj < 8; ++nj) {
      atomicAdd(&ls[nj * 16 + l15], cs[nj]);
      atomicAdd(&ls[128 + nj * 16 + l15], cq[nj]);
    }
  }
  __syncthreads();
  if (tid < 128) {
    atomicAdd(&gsum[tid], ls[tid]);
    atomicAdd(&gsq[tid], ls[128 + tid]);
  }
}

// ---------------- BN apply (scale/shift derived in-kernel) + relu ----------------
__global__ __launch_bounds__(256) void k_apply(float* __restrict__ out,
                                               const float* __restrict__ gsum,
                                               const float* __restrict__ gsq,
                                               const float* __restrict__ gamma,
                                               const float* __restrict__ beta) {
  const int total4 = NN * DIM / 4;
  int i = blockIdx.x * blockDim.x + threadIdx.x;
  int st = gridDim.x * blockDim.x;   // 1,048,576: multiple of 32 -> (i&31) invariant
  int c4 = (i & 31) * 4;
  float4 su = *(const float4*)(gsum + c4);
  float4 qu = *(const float4*)(gsq + c4);
  float4 ga = *(const float4*)(gamma + c4);
  float4 be = *(const float4*)(beta + c4);
  float4 s, sh;
  {
    float m, v;
    m = su.x * (1.0f / NN); v = fmaxf(qu.x * (1.0f / NN) - m * m, 0.f);
    s.x = ga.x * rsqrtf(v + 1e-5f); sh.x = be.x - m * s.x;
    m = su.y * (1.0f / NN); v = fmaxf(qu.y * (1.0f / NN) - m * m, 0.f);
    s.y = ga.y * rsqrtf(v + 1e-5f); sh.y = be.y - m * s.y;
    m = su.z * (1.0f / NN); v = fmaxf(qu.z * (1.0f / NN) - m * m, 0.f);
    s.z = ga.z * rsqrtf(v + 1e-5f); sh.z = be.z - m * s.z;
    m = su.w * (1.0f / NN); v = fmaxf(qu.w * (1.0f / NN) - m * m, 0.f);
    s.w = ga.w * rsqrtf(v + 1e-5f); sh.w = be.w - m * s.w;
  }
  for (int i4 = i; i4 < total4; i4 += st) {
    float4 v = ((float4*)out)[i4];
    v.x = fmaxf(fmaf(v.x, s.x, sh.x), 0.f);
    v.y = fmaxf(fmaf(v.y, s.y, sh.y), 0.f);
    v.z = fmaxf(fmaf(v.z, s.z, sh.z), 0.f);
    v.w = fmaxf(fmaf(v.w, s.w, sh.w), 0.f);
    ((float4*)out)[i4] = v;
  }
}

extern "C" void kernel_launch(void* const* d_in, const int* in_sizes, int n_in,
                              void* d_out, int out_size, void* d_ws, size_t ws_size,
                              hipStream_t stream) {
  const float* feature = (const float*)d_in[0];
  const float* snorm   = (const float*)d_in[1];
  const int*   src     = (const int*)d_in[2];
  const int*   dst     = (const int*)d_in[3];
  const float* W       = (const float*)d_in[4];
  const float* bias    = (const float*)d_in[5];
  const float* gamma   = (const float*)d_in[6];
  const float* beta    = (const float*)d_in[7];
  float* out = (float*)d_out;

  const size_t TBL = (size_t)NN * 64 * sizeof(u32);  // 25.6 MB
  char* p = (char*)d_ws;
  u32* X0b = (u32*)p; p += TBL;
  u32* Y0  = (u32*)p; p += TBL;   // reused as X2b after prop1 consumes it
  u32* X1b = (u32*)p; p += TBL;   // epair (12.8 MB) aliases this until k_fine done
  u32* Y1  = (u32*)p; p += TBL;
  u32* X2b = Y0;
  int2* epair = (int2*)X1b;
  u32* Wf  = (u32*)p; p += 96 * 256 * sizeof(u32);   // 98.3 KB
  int* esrc = (int*)p;    p += (size_t)EE * 4;
  int* rp   = (int*)p;    p += ((size_t)(NN + 1) * 4 + 127) & ~(size_t)127;
  float* ds = (float*)p;  p += (size_t)NN * 4;
  int* hist_t   = (int*)p; p += (size_t)NBUCK * B1 * 4;  // 200 KB
  int* blockoff = (int*)p; p += (size_t)NBUCK * B1 * 4;  // 200 KB
  int* btot  = (int*)p;   p += 512 * 4;
  int* bbase = (int*)p;   p += 512 * 4;
  char* zbeg = p;
  float* gsum = (float*)p; p += 512;
  float* gsq  = (float*)p; p += 512;

  hipMemsetAsync(zbeg, 0, 1024, stream);  // gsum, gsq

  k_hist<<<B1, 256, 0, stream>>>(dst, hist_t);
  k_boff<<<NBUCK, B1, 0, stream>>>(hist_t, blockoff, btot);
  k_bbase<<<1, 512, 0, stream>>>(btot, bbase);
  k_bucket<<<B1, 256, 0, stream>>>(src, dst, bbase, blockoff, epair);
  k_fine<<<NBUCK, 256, 0, stream>>>(epair, bbase, rp, ds, esrc);
  k_prep<<<4096, 256, 0, stream>>>(feature, ds, X0b, Y0, W, Wf);
  k_prop1<<<NN / 4, 256, 0, stream>>>(Y0, ds, rp, esrc, X1b, Y1);
  k_prop2<<<NN / 4, 256, 0, stream>>>(Y1, X0b, ds, rp, esrc, X2b);
  k_gemm<<<(NN + 511) / 512, 1024, 0, stream>>>(X0b, X1b, X2b, Wf, bias, snorm,
                                                out, gsum, gsq);
  k_apply<<<4096, 256, 0, stream>>>(out, gsum, gsq, gamma, beta);
}

// Round 8
// 279.924 us; speedup vs baseline: 1.6429x; 1.6429x over previous
//
#include <hip/hip_runtime.h>

#define NN 100000
#define EE 1600000
#define DIM 128
#define NBUCK ((NN + 255) >> 8)   // 391 buckets of 256 nodes
#define B1 128                    // bucket-pass blocks
#define CH ((EE + B1 - 1) / B1)   // 12500 edges per block

typedef unsigned int u32;
typedef __attribute__((ext_vector_type(8))) short bf16x8;
typedef __attribute__((ext_vector_type(4))) float f32x4;

union U4 { uint4 u; bf16x8 h; };

__device__ __forceinline__ float lof(u32 u) { return __uint_as_float(u << 16); }
__device__ __forceinline__ float hif(u32 u) { return __uint_as_float(u & 0xffff0000u); }
__device__ __forceinline__ u32 pack_bf2(float a, float b) {
  u32 ua = __float_as_uint(a), ub = __float_as_uint(b);
  ua = (ua + 0x7fffu + ((ua >> 16) & 1u)) >> 16;
  ub = (ub + 0x7fffu + ((ub >> 16) & 1u)) & 0xffff0000u;
  return ua | ub;
}

// ---------------- pass A: per-block bucket histogram ----------------
__global__ __launch_bounds__(256) void k_hist(const int* __restrict__ dst,
                                              int* __restrict__ hist_t) {
  __shared__ int h[NBUCK];
  for (int i = threadIdx.x; i < NBUCK; i += 256) h[i] = 0;
  __syncthreads();
  int e0 = blockIdx.x * CH;
  int e1 = e0 + CH < EE ? e0 + CH : EE;
  for (int e = e0 + threadIdx.x; e < e1; e += 256)
    atomicAdd(&h[dst[e] >> 8], 1);
  __syncthreads();
  for (int i = threadIdx.x; i < NBUCK; i += 256)
    hist_t[i * B1 + blockIdx.x] = h[i];
}

// ---------------- pass B: per-bucket scan over blocks ----------------
__global__ __launch_bounds__(B1) void k_boff(const int* __restrict__ hist_t,
                                             int* __restrict__ blockoff,
                                             int* __restrict__ btot) {
  __shared__ int ps[B1];
  int j = blockIdx.x, t = threadIdx.x;
  int v = hist_t[j * B1 + t];
  ps[t] = v;
  __syncthreads();
  #pragma unroll
  for (int off = 1; off < B1; off <<= 1) {
    int u = (t >= off) ? ps[t - off] : 0;
    __syncthreads();
    ps[t] += u;
    __syncthreads();
  }
  blockoff[j * B1 + t] = ps[t] - v;
  if (t == B1 - 1) btot[j] = ps[t];
}

// ---------------- pass B2: scan bucket totals -> bbase ----------------
__global__ __launch_bounds__(512) void k_bbase(const int* __restrict__ btot,
                                               int* __restrict__ bbase) {
  __shared__ int ps[512];
  int t = threadIdx.x;
  int v = (t < NBUCK) ? btot[t] : 0;
  ps[t] = v;
  __syncthreads();
  #pragma unroll
  for (int off = 1; off < 512; off <<= 1) {
    int u = (t >= off) ? ps[t - off] : 0;
    __syncthreads();
    ps[t] += u;
    __syncthreads();
  }
  if (t < NBUCK) bbase[t] = ps[t] - v;
  if (t == 0) bbase[NBUCK] = EE;
}

// ---------------- pass C: scatter (dst,src) pairs into bucket regions ----------------
__global__ __launch_bounds__(256) void k_bucket(const int* __restrict__ src,
                                                const int* __restrict__ dst,
                                                const int* __restrict__ bbase,
                                                const int* __restrict__ blockoff,
                                                int2* __restrict__ epair) {
  __shared__ int cnt[NBUCK];
  for (int i = threadIdx.x; i < NBUCK; i += 256) cnt[i] = 0;
  __syncthreads();
  int e0 = blockIdx.x * CH;
  int e1 = e0 + CH < EE ? e0 + CH : EE;
  for (int e = e0 + threadIdx.x; e < e1; e += 256) {
    int d = dst[e], s = src[e];
    int j = d >> 8;
    int loc = atomicAdd(&cnt[j], 1);
    epair[bbase[j] + blockoff[j * B1 + blockIdx.x] + loc] = make_int2(d, s);
  }
}

// ---------------- pass D: per-bucket deg/ds/rp + fine scatter -> esrc ----------------
__global__ __launch_bounds__(256) void k_fine(const int2* __restrict__ epair,
                                              const int* __restrict__ bbase,
                                              int* __restrict__ rp,
                                              float* __restrict__ ds,
                                              int* __restrict__ esrc) {
  __shared__ int cntA[256], cntB[256], rpl[256], ps[256];
  int j = blockIdx.x, t = threadIdx.x;
  int node0 = j << 8;
  int e0 = bbase[j], e1 = bbase[j + 1];
  cntA[t] = 0;
  cntB[t] = 0;
  __syncthreads();
  for (int e = e0 + t; e < e1; e += 256)
    atomicAdd(&cntA[epair[e].x & 255], 1);
  __syncthreads();
  int deg = cntA[t];
  ps[t] = deg;
  __syncthreads();
  #pragma unroll
  for (int off = 1; off < 256; off <<= 1) {
    int u = (t >= off) ? ps[t - off] : 0;
    __syncthreads();
    ps[t] += u;
    __syncthreads();
  }
  rpl[t] = e0 + ps[t] - deg;
  __syncthreads();
  int node = node0 + t;
  if (node < NN) {
    rp[node] = rpl[t];
    ds[node] = rsqrtf(fmaxf((float)deg, 1.0f));
  }
  if (j == 0 && t == 0) rp[NN] = EE;
  for (int e = e0 + t; e < e1; e += 256) {
    int2 pr = epair[e];
    int d = pr.x & 255;
    int pos = rpl[d] + atomicAdd(&cntB[d], 1);
    esrc[pos] = pr.y;
  }
}

// ---------------- prep: X0b/Y0 tables + fused Wf (fragment-major bf16 W) ----
__global__ void k_prep(const float* __restrict__ feature, const float* __restrict__ ds,
                       u32* __restrict__ X0b, u32* __restrict__ Y0,
                       const float* __restrict__ W, u32* __restrict__ Wf) {
  int i = blockIdx.x * blockDim.x + threadIdx.x;
  if (i < 96 * 256) {
    // Wf u32 index = ((phase*4+ks)*8+nj)*256 + lane*4 + j
    int fi = i >> 8;
    int lane = (i >> 2) & 63;
    int jj = i & 3;
    int phase = fi >> 5, ks = (fi >> 3) & 3, nj = fi & 7;
    int g = lane >> 4, l15 = lane & 15;
    int nn = nj * 16 + l15;
    int ku = phase * 64 + ks * 16 + g * 4 + jj;
    int k = ku * 2;
    float w0 = W[(size_t)k * 128 + nn];
    float w1 = W[(size_t)(k + 1) * 128 + nn];
    Wf[i] = pack_bf2(w0, w1);
  }
  const int total = NN * 32;  // uint2 count (4 dims each)
  int st = gridDim.x * blockDim.x;
  for (int j = i; j < total; j += st) {
    int n = j >> 5;
    float4 f = *(const float4*)(feature + (size_t)n * DIM + (j & 31) * 4);
    float dsn = ds[n];
    ((uint2*)X0b)[j] = make_uint2(pack_bf2(f.x, f.y), pack_bf2(f.z, f.w));
    ((uint2*)Y0)[j] = make_uint2(pack_bf2(f.x * dsn, f.y * dsn),
                                 pack_bf2(f.z * dsn, f.w * dsn));
  }
}

// ---------------- prop1: X1 = -ds[n]*sum Y0[s]; write X1b, Y1 = X1*ds[n] ----------------
// Branch-free 8-wide + 4-wide gather batches (MLP), scalar tail.
__global__ __launch_bounds__(256) void k_prop1(const u32* __restrict__ Y0,
                                               const float* __restrict__ ds,
                                               const int* __restrict__ rp,
                                               const int* __restrict__ esrc,
                                               u32* __restrict__ X1b,
                                               u32* __restrict__ Y1) {
  int n = blockIdx.x * 4 + (threadIdx.x >> 6);
  int l = threadIdx.x & 63;
  int beg = rp[n], end = rp[n + 1];
  float ax[8], ay[8];
  #pragma unroll
  for (int i = 0; i < 8; ++i) { ax[i] = 0.f; ay[i] = 0.f; }
  int p = beg;
  for (; p + 8 <= end; p += 8) {
    int s[8];
    #pragma unroll
    for (int i = 0; i < 8; ++i) s[i] = esrc[p + i];
    u32 u[8];
    #pragma unroll
    for (int i = 0; i < 8; ++i) u[i] = Y0[(size_t)s[i] * 64 + l];
    #pragma unroll
    for (int i = 0; i < 8; ++i) { ax[i] += lof(u[i]); ay[i] += hif(u[i]); }
  }
  if (p + 4 <= end) {
    int s[4];
    #pragma unroll
    for (int i = 0; i < 4; ++i) s[i] = esrc[p + i];
    u32 u[4];
    #pragma unroll
    for (int i = 0; i < 4; ++i) u[i] = Y0[(size_t)s[i] * 64 + l];
    #pragma unroll
    for (int i = 0; i < 4; ++i) { ax[i] += lof(u[i]); ay[i] += hif(u[i]); }
    p += 4;
  }
  for (; p < end; ++p) {
    u32 u = Y0[(size_t)esrc[p] * 64 + l];
    ax[0] += lof(u); ay[0] += hif(u);
  }
  float sx = ((ax[0] + ax[4]) + (ax[2] + ax[6])) + ((ax[1] + ax[5]) + (ax[3] + ax[7]));
  float sy = ((ay[0] + ay[4]) + (ay[2] + ay[6])) + ((ay[1] + ay[5]) + (ay[3] + ay[7]));
  float dsn = ds[n];
  float x = -dsn * sx;
  float y = -dsn * sy;
  X1b[(size_t)n * 64 + l] = pack_bf2(x, y);
  Y1[(size_t)n * 64 + l] = pack_bf2(x * dsn, y * dsn);
}

// ---------------- prop2: X2 = -2*ds[n]*sum Y1[s] - X0 ----------------
__global__ __launch_bounds__(256) void k_prop2(const u32* __restrict__ Y1,
                                               const u32* __restrict__ X0b,
                                               const float* __restrict__ ds,
                                               const int* __restrict__ rp,
                                               const int* __restrict__ esrc,
                                               u32* __restrict__ X2b) {
  int n = blockIdx.x * 4 + (threadIdx.x >> 6);
  int l = threadIdx.x & 63;
  int beg = rp[n], end = rp[n + 1];
  float ax[8], ay[8];
  #pragma unroll
  for (int i = 0; i < 8; ++i) { ax[i] = 0.f; ay[i] = 0.f; }
  int p = beg;
  for (; p + 8 <= end; p += 8) {
    int s[8];
    #pragma unroll
    for (int i = 0; i < 8; ++i) s[i] = esrc[p + i];
    u32 u[8];
    #pragma unroll
    for (int i = 0; i < 8; ++i) u[i] = Y1[(size_t)s[i] * 64 + l];
    #pragma unroll
    for (int i = 0; i < 8; ++i) { ax[i] += lof(u[i]); ay[i] += hif(u[i]); }
  }
  if (p + 4 <= end) {
    int s[4];
    #pragma unroll
    for (int i = 0; i < 4; ++i) s[i] = esrc[p + i];
    u32 u[4];
    #pragma unroll
    for (int i = 0; i < 4; ++i) u[i] = Y1[(size_t)s[i] * 64 + l];
    #pragma unroll
    for (int i = 0; i < 4; ++i) { ax[i] += lof(u[i]); ay[i] += hif(u[i]); }
    p += 4;
  }
  for (; p < end; ++p) {
    u32 u = Y1[(size_t)esrc[p] * 64 + l];
    ax[0] += lof(u); ay[0] += hif(u);
  }
  float sx = ((ax[0] + ax[4]) + (ax[2] + ax[6])) + ((ax[1] + ax[5]) + (ax[3] + ax[7]));
  float sy = ((ay[0] + ay[4]) + (ay[2] + ay[6])) + ((ay[1] + ay[5]) + (ay[3] + ay[7]));
  float dsn = ds[n];
  u32 u0 = X0b[(size_t)n * 64 + l];
  float x = -2.0f * dsn * sx - lof(u0);
  float y = -2.0f * dsn * sy - hif(u0);
  X2b[(size_t)n * 64 + l] = pack_bf2(x, y);
}

// ---------------- MFMA GEMM with LDS-staged fragment-major W ----------------
__global__ __launch_bounds__(1024) void k_gemm(const u32* __restrict__ X0b,
                                               const u32* __restrict__ X1b,
                                               const u32* __restrict__ X2b,
                                               const u32* __restrict__ Wf,
                                               const float* __restrict__ bias,
                                               const float* __restrict__ snorm,
                                               float* __restrict__ out,
                                               float* __restrict__ gsum,
                                               float* __restrict__ gsq) {
  __shared__ u32 wlds[24576];   // 96 KB
  __shared__ float ls[256];
  int tid = threadIdx.x;
  #pragma unroll
  for (int l = 0; l < 6; ++l) {
    int it = tid + l * 1024;
    ((uint4*)wlds)[it] = ((const uint4*)Wf)[it];
  }
  int wid = tid >> 6, lane = tid & 63;
  int l15 = lane & 15, g = lane >> 4;
  int row0 = blockIdx.x * 512 + wid * 32;
  bool active = (row0 + 32) <= NN;
  if (!active) row0 = 0;

  size_t rb0 = (size_t)(row0 + l15) * 64 + g * 4;
  size_t rb1 = rb0 + (size_t)16 * 64;

  f32x4 acc[2][8];
  #pragma unroll
  for (int mi = 0; mi < 2; ++mi)
    #pragma unroll
    for (int nj = 0; nj < 8; ++nj) acc[mi][nj] = (f32x4){0.f, 0.f, 0.f, 0.f};

  __syncthreads();

  const u32* tabs[3] = {X0b, X1b, X2b};
  #pragma unroll
  for (int phase = 0; phase < 3; ++phase) {
    const u32* A = tabs[phase];
    #pragma unroll
    for (int ks = 0; ks < 4; ++ks) {
      U4 a0, a1;
      a0.u = *(const uint4*)(A + rb0 + ks * 16);
      a1.u = *(const uint4*)(A + rb1 + ks * 16);
      #pragma unroll
      for (int nj = 0; nj < 8; ++nj) {
        U4 b;
        b.u = ((const uint4*)wlds)[((phase * 4 + ks) * 8 + nj) * 64 + lane];
        acc[0][nj] = __builtin_amdgcn_mfma_f32_16x16x32_bf16(a0.h, b.h, acc[0][nj], 0, 0, 0);
        acc[1][nj] = __builtin_amdgcn_mfma_f32_16x16x32_bf16(a1.h, b.h, acc[1][nj], 0, 0, 0);
      }
    }
  }

  float cs[8], cq[8];
  #pragma unroll
  for (int nj = 0; nj < 8; ++nj) { cs[nj] = 0.f; cq[nj] = 0.f; }
  if (active) {
    float bs[8];
    #pragma unroll
    for (int nj = 0; nj < 8; ++nj) bs[nj] = bias[nj * 16 + l15];
    #pragma unroll
    for (int mi = 0; mi < 2; ++mi) {
      #pragma unroll
      for (int r = 0; r < 4; ++r) {
        int row = row0 + mi * 16 + g * 4 + r;
        float sn = snorm[row];
        #pragma unroll
        for (int nj = 0; nj < 8; ++nj) {
          float h = (acc[mi][nj][r] + bs[nj]) * sn;
          out[(size_t)row * DIM + nj * 16 + l15] = h;
          cs[nj] += h;
          cq[nj] += h * h;
        }
      }
    }
  }
  if (tid < 256) ls[tid] = 0.f;
  __syncthreads();
  if (active) {
    #pragma unroll
    for (int nj = 0; nj < 8; ++nj) {
      atomicAdd(&ls[nj * 16 + l15], cs[nj]);
      atomicAdd(&ls[128 + nj * 16 + l15], cq[nj]);
    }
  }
  __syncthreads();
  if (tid < 128) {
    atomicAdd(&gsum[tid], ls[tid]);
    atomicAdd(&gsq[tid], ls[128 + tid]);
  }
}

// ---------------- BN apply (scale/shift derived in-kernel) + relu ----------------
__global__ __launch_bounds__(256) void k_apply(float* __restrict__ out,
                                               const float* __restrict__ gsum,
                                               const float* __restrict__ gsq,
                                               const float* __restrict__ gamma,
                                               const float* __restrict__ beta) {
  const int total4 = NN * DIM / 4;
  int i = blockIdx.x * blockDim.x + threadIdx.x;
  int st = gridDim.x * blockDim.x;   // 1,048,576: multiple of 32 -> (i&31) invariant
  int c4 = (i & 31) * 4;
  float4 su = *(const float4*)(gsum + c4);
  float4 qu = *(const float4*)(gsq + c4);
  float4 ga = *(const float4*)(gamma + c4);
  float4 be = *(const float4*)(beta + c4);
  float4 s, sh;
  {
    float m, v;
    m = su.x * (1.0f / NN); v = fmaxf(qu.x * (1.0f / NN) - m * m, 0.f);
    s.x = ga.x * rsqrtf(v + 1e-5f); sh.x = be.x - m * s.x;
    m = su.y * (1.0f / NN); v = fmaxf(qu.y * (1.0f / NN) - m * m, 0.f);
    s.y = ga.y * rsqrtf(v + 1e-5f); sh.y = be.y - m * s.y;
    m = su.z * (1.0f / NN); v = fmaxf(qu.z * (1.0f / NN) - m * m, 0.f);
    s.z = ga.z * rsqrtf(v + 1e-5f); sh.z = be.z - m * s.z;
    m = su.w * (1.0f / NN); v = fmaxf(qu.w * (1.0f / NN) - m * m, 0.f);
    s.w = ga.w * rsqrtf(v + 1e-5f); sh.w = be.w - m * s.w;
  }
  for (int i4 = i; i4 < total4; i4 += st) {
    float4 v = ((float4*)out)[i4];
    v.x = fmaxf(fmaf(v.x, s.x, sh.x), 0.f);
    v.y = fmaxf(fmaf(v.y, s.y, sh.y), 0.f);
    v.z = fmaxf(fmaf(v.z, s.z, sh.z), 0.f);
    v.w = fmaxf(fmaf(v.w, s.w, sh.w), 0.f);
    ((float4*)out)[i4] = v;
  }
}

extern "C" void kernel_launch(void* const* d_in, const int* in_sizes, int n_in,
                              void* d_out, int out_size, void* d_ws, size_t ws_size,
                              hipStream_t stream) {
  const float* feature = (const float*)d_in[0];
  const float* snorm   = (const float*)d_in[1];
  const int*   src     = (const int*)d_in[2];
  const int*   dst     = (const int*)d_in[3];
  const float* W       = (const float*)d_in[4];
  const float* bias    = (const float*)d_in[5];
  const float* gamma   = (const float*)d_in[6];
  const float* beta    = (const float*)d_in[7];
  float* out = (float*)d_out;

  const size_t TBL = (size_t)NN * 64 * sizeof(u32);  // 25.6 MB
  char* p = (char*)d_ws;
  u32* X0b = (u32*)p; p += TBL;
  u32* Y0  = (u32*)p; p += TBL;   // reused as X2b after prop1 consumes it
  u32* X1b = (u32*)p; p += TBL;   // epair (12.8 MB) aliases this until k_fine done
  u32* Y1  = (u32*)p; p += TBL;
  u32* X2b = Y0;
  int2* epair = (int2*)X1b;
  u32* Wf  = (u32*)p; p += 96 * 256 * sizeof(u32);   // 98.3 KB
  int* esrc = (int*)p;    p += (size_t)EE * 4;
  int* rp   = (int*)p;    p += ((size_t)(NN + 1) * 4 + 127) & ~(size_t)127;
  float* ds = (float*)p;  p += (size_t)NN * 4;
  int* hist_t   = (int*)p; p += (size_t)NBUCK * B1 * 4;  // 200 KB
  int* blockoff = (int*)p; p += (size_t)NBUCK * B1 * 4;  // 200 KB
  int* btot  = (int*)p;   p += 512 * 4;
  int* bbase = (int*)p;   p += 512 * 4;
  char* zbeg = p;
  float* gsum = (float*)p; p += 512;
  float* gsq  = (float*)p; p += 512;

  hipMemsetAsync(zbeg, 0, 1024, stream);  // gsum, gsq

  k_hist<<<B1, 256, 0, stream>>>(dst, hist_t);
  k_boff<<<NBUCK, B1, 0, stream>>>(hist_t, blockoff, btot);
  k_bbase<<<1, 512, 0, stream>>>(btot, bbase);
  k_bucket<<<B1, 256, 0, stream>>>(src, dst, bbase, blockoff, epair);
  k_fine<<<NBUCK, 256, 0, stream>>>(epair, bbase, rp, ds, esrc);
  k_prep<<<4096, 256, 0, stream>>>(feature, ds, X0b, Y0, W, Wf);
  k_prop1<<<NN / 4, 256, 0, stream>>>(Y0, ds, rp, esrc, X1b, Y1);
  k_prop2<<<NN / 4, 256, 0, stream>>>(Y1, X0b, ds, rp, esrc, X2b);
  k_gemm<<<(NN + 511) / 512, 1024, 0, stream>>>(X0b, X1b, X2b, Wf, bias, snorm,
                                                out, gsum, gsq);
  k_apply<<<4096, 256, 0, stream>>>(out, gsum, gsq, gamma, beta);
}

// Round 9
// 274.524 us; speedup vs baseline: 1.6752x; 1.0197x over previous
//
#include <hip/hip_runtime.h>

#define NN 100000
#define EE 1600000
#define DIM 128
#define NBUCK ((NN + 255) >> 8)   // 391 buckets of 256 nodes
#define B1 128                    // bucket-pass blocks
#define CH ((EE + B1 - 1) / B1)   // 12500 edges per block

typedef unsigned int u32;
typedef __attribute__((ext_vector_type(8))) short bf16x8;
typedef __attribute__((ext_vector_type(4))) float f32x4;

union U4 { uint4 u; bf16x8 h; };

__device__ __forceinline__ float lof(u32 u) { return __uint_as_float(u << 16); }
__device__ __forceinline__ float hif(u32 u) { return __uint_as_float(u & 0xffff0000u); }
__device__ __forceinline__ u32 pack_bf2(float a, float b) {
  u32 ua = __float_as_uint(a), ub = __float_as_uint(b);
  ua = (ua + 0x7fffu + ((ua >> 16) & 1u)) >> 16;
  ub = (ub + 0x7fffu + ((ub >> 16) & 1u)) & 0xffff0000u;
  return ua | ub;
}

// ---------------- pass A: per-block bucket histogram ----------------
__global__ __launch_bounds__(256) void k_hist(const int* __restrict__ dst,
                                              int* __restrict__ hist_t) {
  __shared__ int h[NBUCK];
  for (int i = threadIdx.x; i < NBUCK; i += 256) h[i] = 0;
  __syncthreads();
  int e0 = blockIdx.x * CH;
  int e1 = e0 + CH < EE ? e0 + CH : EE;
  for (int e = e0 + threadIdx.x; e < e1; e += 256)
    atomicAdd(&h[dst[e] >> 8], 1);
  __syncthreads();
  for (int i = threadIdx.x; i < NBUCK; i += 256)
    hist_t[i * B1 + blockIdx.x] = h[i];
}

// ---------------- pass B: per-bucket scan over blocks ----------------
__global__ __launch_bounds__(B1) void k_boff(const int* __restrict__ hist_t,
                                             int* __restrict__ blockoff,
                                             int* __restrict__ btot) {
  __shared__ int ps[B1];
  int j = blockIdx.x, t = threadIdx.x;
  int v = hist_t[j * B1 + t];
  ps[t] = v;
  __syncthreads();
  #pragma unroll
  for (int off = 1; off < B1; off <<= 1) {
    int u = (t >= off) ? ps[t - off] : 0;
    __syncthreads();
    ps[t] += u;
    __syncthreads();
  }
  blockoff[j * B1 + t] = ps[t] - v;
  if (t == B1 - 1) btot[j] = ps[t];
}

// ---------------- pass B2: scan bucket totals -> bbase ----------------
__global__ __launch_bounds__(512) void k_bbase(const int* __restrict__ btot,
                                               int* __restrict__ bbase) {
  __shared__ int ps[512];
  int t = threadIdx.x;
  int v = (t < NBUCK) ? btot[t] : 0;
  ps[t] = v;
  __syncthreads();
  #pragma unroll
  for (int off = 1; off < 512; off <<= 1) {
    int u = (t >= off) ? ps[t - off] : 0;
    __syncthreads();
    ps[t] += u;
    __syncthreads();
  }
  if (t < NBUCK) bbase[t] = ps[t] - v;
  if (t == 0) bbase[NBUCK] = EE;
}

// ---------------- pass C: scatter packed (src<<8|dlow) into bucket regions ----------------
__global__ __launch_bounds__(256) void k_bucket(const int* __restrict__ src,
                                                const int* __restrict__ dst,
                                                const int* __restrict__ bbase,
                                                const int* __restrict__ blockoff,
                                                u32* __restrict__ epair) {
  __shared__ int cnt[NBUCK];
  for (int i = threadIdx.x; i < NBUCK; i += 256) cnt[i] = 0;
  __syncthreads();
  int e0 = blockIdx.x * CH;
  int e1 = e0 + CH < EE ? e0 + CH : EE;
  for (int e = e0 + threadIdx.x; e < e1; e += 256) {
    int d = dst[e], s = src[e];
    int j = d >> 8;
    int loc = atomicAdd(&cnt[j], 1);
    epair[bbase[j] + blockoff[j * B1 + blockIdx.x] + loc] =
        ((u32)s << 8) | (u32)(d & 255);
  }
}

// ---------------- pass D: per-bucket deg/ds/rp + fine scatter -> esrc ----------------
__global__ __launch_bounds__(256) void k_fine(const u32* __restrict__ epair,
                                              const int* __restrict__ bbase,
                                              int* __restrict__ rp,
                                              float* __restrict__ ds,
                                              int* __restrict__ esrc) {
  __shared__ int cntA[256], cntB[256], rpl[256], ps[256];
  int j = blockIdx.x, t = threadIdx.x;
  int node0 = j << 8;
  int e0 = bbase[j], e1 = bbase[j + 1];
  cntA[t] = 0;
  cntB[t] = 0;
  __syncthreads();
  for (int e = e0 + t; e < e1; e += 256)
    atomicAdd(&cntA[epair[e] & 255], 1);
  __syncthreads();
  int deg = cntA[t];
  ps[t] = deg;
  __syncthreads();
  #pragma unroll
  for (int off = 1; off < 256; off <<= 1) {
    int u = (t >= off) ? ps[t - off] : 0;
    __syncthreads();
    ps[t] += u;
    __syncthreads();
  }
  rpl[t] = e0 + ps[t] - deg;
  __syncthreads();
  int node = node0 + t;
  if (node < NN) {
    rp[node] = rpl[t];
    ds[node] = rsqrtf(fmaxf((float)deg, 1.0f));
  }
  if (j == 0 && t == 0) { rp[NN] = EE; ds[NN] = 0.f; }
  for (int e = e0 + t; e < e1; e += 256) {
    u32 pv = epair[e];
    int d = pv & 255;
    int pos = rpl[d] + atomicAdd(&cntB[d], 1);
    esrc[pos] = (int)(pv >> 8);
  }
}

// ---------------- prep: X0b/Y0 tables + sentinels + fused Wf ----------------
__global__ void k_prep(const float* __restrict__ feature, const float* __restrict__ ds,
                       u32* __restrict__ X0b, u32* __restrict__ Y0,
                       u32* __restrict__ X1b,
                       const float* __restrict__ W, u32* __restrict__ Wf) {
  int i = blockIdx.x * blockDim.x + threadIdx.x;
  if (i < 96 * 256) {
    // Wf u32 index = ((phase*4+ks)*8+nj)*256 + lane*4 + j
    int fi = i >> 8;
    int lane = (i >> 2) & 63;
    int jj = i & 3;
    int phase = fi >> 5, ks = (fi >> 3) & 3, nj = fi & 7;
    int g = lane >> 4, l15 = lane & 15;
    int nn = nj * 16 + l15;
    int ku = phase * 64 + ks * 16 + g * 4 + jj;
    int k = ku * 2;
    float w0 = W[(size_t)k * 128 + nn];
    float w1 = W[(size_t)(k + 1) * 128 + nn];
    Wf[i] = pack_bf2(w0, w1);
  }
  if (i < 64) {  // zero sentinel rows (gather target for padded slots)
    Y0[(size_t)NN * 64 + i] = 0u;
    X1b[(size_t)NN * 64 + i] = 0u;
  }
  const int total = NN * 32;  // uint2 count (4 dims each)
  int st = gridDim.x * blockDim.x;
  for (int j = i; j < total; j += st) {
    int n = j >> 5;
    float4 f = *(const float4*)(feature + (size_t)n * DIM + (j & 31) * 4);
    float dsn = ds[n];
    ((uint2*)X0b)[j] = make_uint2(pack_bf2(f.x, f.y), pack_bf2(f.z, f.w));
    ((uint2*)Y0)[j] = make_uint2(pack_bf2(f.x * dsn, f.y * dsn),
                                 pack_bf2(f.z * dsn, f.w * dsn));
  }
}

// ---------------- prop1: X1 = -ds[n]*sum Y0[s] ----------------
// Sentinel-padded branch-free 8-batches: unconditional esrc load + register
// select to zero-row NN (no exec-mask branch -> full MLP, no tail loop).
__global__ __launch_bounds__(256) void k_prop1(const u32* __restrict__ Y0,
                                               const float* __restrict__ ds,
                                               const int* __restrict__ rp,
                                               const int* __restrict__ esrc,
                                               u32* __restrict__ X1b) {
  int n = blockIdx.x * 4 + (threadIdx.x >> 6);
  int l = threadIdx.x & 63;
  int beg = rp[n], end = rp[n + 1];
  int end8 = beg + ((end - beg + 7) & ~7);
  float ax[8], ay[8];
  #pragma unroll
  for (int i = 0; i < 8; ++i) { ax[i] = 0.f; ay[i] = 0.f; }
  for (int p = beg; p < end8; p += 8) {
    int s[8];
    #pragma unroll
    for (int i = 0; i < 8; ++i) {
      int q = p + i;
      int ev = esrc[q];          // unconditional (esrc padded by 8)
      s[i] = (q < end) ? ev : NN;  // register select, no branch
    }
    u32 u[8];
    #pragma unroll
    for (int i = 0; i < 8; ++i) u[i] = Y0[(size_t)s[i] * 64 + l];
    #pragma unroll
    for (int i = 0; i < 8; ++i) { ax[i] += lof(u[i]); ay[i] += hif(u[i]); }
  }
  float sx = ((ax[0] + ax[4]) + (ax[2] + ax[6])) + ((ax[1] + ax[5]) + (ax[3] + ax[7]));
  float sy = ((ay[0] + ay[4]) + (ay[2] + ay[6])) + ((ay[1] + ay[5]) + (ay[3] + ay[7]));
  float dsn = ds[n];
  X1b[(size_t)n * 64 + l] = pack_bf2(-dsn * sx, -dsn * sy);
}

// ---------------- prop2: X2 = -2*ds[n]*sum X1[s]*ds[s] - X0 ----------------
__global__ __launch_bounds__(256) void k_prop2(const u32* __restrict__ X1b,
                                               const u32* __restrict__ X0b,
                                               const float* __restrict__ ds,
                                               const int* __restrict__ rp,
                                               const int* __restrict__ esrc,
                                               u32* __restrict__ X2b) {
  int n = blockIdx.x * 4 + (threadIdx.x >> 6);
  int l = threadIdx.x & 63;
  int beg = rp[n], end = rp[n + 1];
  int end8 = beg + ((end - beg + 7) & ~7);
  float ax[8], ay[8];
  #pragma unroll
  for (int i = 0; i < 8; ++i) { ax[i] = 0.f; ay[i] = 0.f; }
  for (int p = beg; p < end8; p += 8) {
    int s[8];
    #pragma unroll
    for (int i = 0; i < 8; ++i) {
      int q = p + i;
      int ev = esrc[q];
      s[i] = (q < end) ? ev : NN;
    }
    u32 u[8];
    float dv[8];
    #pragma unroll
    for (int i = 0; i < 8; ++i) {
      u[i] = X1b[(size_t)s[i] * 64 + l];
      dv[i] = ds[s[i]];
    }
    #pragma unroll
    for (int i = 0; i < 8; ++i) {
      ax[i] = fmaf(lof(u[i]), dv[i], ax[i]);
      ay[i] = fmaf(hif(u[i]), dv[i], ay[i]);
    }
  }
  float sx = ((ax[0] + ax[4]) + (ax[2] + ax[6])) + ((ax[1] + ax[5]) + (ax[3] + ax[7]));
  float sy = ((ay[0] + ay[4]) + (ay[2] + ay[6])) + ((ay[1] + ay[5]) + (ay[3] + ay[7]));
  float dsn = ds[n];
  u32 u0 = X0b[(size_t)n * 64 + l];
  float x = -2.0f * dsn * sx - lof(u0);
  float y = -2.0f * dsn * sy - hif(u0);
  X2b[(size_t)n * 64 + l] = pack_bf2(x, y);
}

// ---------------- MFMA GEMM with LDS-staged fragment-major W ----------------
__global__ __launch_bounds__(1024) void k_gemm(const u32* __restrict__ X0b,
                                               const u32* __restrict__ X1b,
                                               const u32* __restrict__ X2b,
                                               const u32* __restrict__ Wf,
                                               const float* __restrict__ bias,
                                               const float* __restrict__ snorm,
                                               float* __restrict__ out,
                                               float* __restrict__ gsum,
                                               float* __restrict__ gsq) {
  __shared__ u32 wlds[24576];   // 96 KB
  __shared__ float ls[256];
  int tid = threadIdx.x;
  #pragma unroll
  for (int l = 0; l < 6; ++l) {
    int it = tid + l * 1024;
    ((uint4*)wlds)[it] = ((const uint4*)Wf)[it];
  }
  int wid = tid >> 6, lane = tid & 63;
  int l15 = lane & 15, g = lane >> 4;
  int row0 = blockIdx.x * 512 + wid * 32;
  bool active = (row0 + 32) <= NN;
  if (!active) row0 = 0;

  size_t rb0 = (size_t)(row0 + l15) * 64 + g * 4;
  size_t rb1 = rb0 + (size_t)16 * 64;

  f32x4 acc[2][8];
  #pragma unroll
  for (int mi = 0; mi < 2; ++mi)
    #pragma unroll
    for (int nj = 0; nj < 8; ++nj) acc[mi][nj] = (f32x4){0.f, 0.f, 0.f, 0.f};

  __syncthreads();

  const u32* tabs[3] = {X0b, X1b, X2b};
  #pragma unroll
  for (int phase = 0; phase < 3; ++phase) {
    const u32* A = tabs[phase];
    #pragma unroll
    for (int ks = 0; ks < 4; ++ks) {
      U4 a0, a1;
      a0.u = *(const uint4*)(A + rb0 + ks * 16);
      a1.u = *(const uint4*)(A + rb1 + ks * 16);
      #pragma unroll
      for (int nj = 0; nj < 8; ++nj) {
        U4 b;
        b.u = ((const uint4*)wlds)[((phase * 4 + ks) * 8 + nj) * 64 + lane];
        acc[0][nj] = __builtin_amdgcn_mfma_f32_16x16x32_bf16(a0.h, b.h, acc[0][nj], 0, 0, 0);
        acc[1][nj] = __builtin_amdgcn_mfma_f32_16x16x32_bf16(a1.h, b.h, acc[1][nj], 0, 0, 0);
      }
    }
  }

  float cs[8], cq[8];
  #pragma unroll
  for (int nj = 0; nj < 8; ++nj) { cs[nj] = 0.f; cq[nj] = 0.f; }
  if (active) {
    float bs[8];
    #pragma unroll
    for (int nj = 0; nj < 8; ++nj) bs[nj] = bias[nj * 16 + l15];
    #pragma unroll
    for (int mi = 0; mi < 2; ++mi) {
      #pragma unroll
      for (int r = 0; r < 4; ++r) {
        int row = row0 + mi * 16 + g * 4 + r;
        float sn = snorm[row];
        #pragma unroll
        for (int nj = 0; nj < 8; ++nj) {
          float h = (acc[mi][nj][r] + bs[nj]) * sn;
          out[(size_t)row * DIM + nj * 16 + l15] = h;
          cs[nj] += h;
          cq[nj] += h * h;
        }
      }
    }
  }
  if (tid < 256) ls[tid] = 0.f;
  __syncthreads();
  if (active) {
    #pragma unroll
    for (int nj = 0; nj < 8; ++nj) {
      atomicAdd(&ls[nj * 16 + l15], cs[nj]);
      atomicAdd(&ls[128 + nj * 16 + l15], cq[nj]);
    }
  }
  __syncthreads();
  if (tid < 128) {
    atomicAdd(&gsum[tid], ls[tid]);
    atomicAdd(&gsq[tid], ls[128 + tid]);
  }
}

// ---------------- BN apply (scale/shift derived in-kernel) + relu ----------------
__global__ __launch_bounds__(256) void k_apply(float* __restrict__ out,
                                               const float* __restrict__ gsum,
                                               const float* __restrict__ gsq,
                                               const float* __restrict__ gamma,
                                               const float* __restrict__ beta) {
  const int total4 = NN * DIM / 4;
  int i = blockIdx.x * blockDim.x + threadIdx.x;
  int st = gridDim.x * blockDim.x;   // multiple of 32 -> (i&31) invariant
  int c4 = (i & 31) * 4;
  float4 su = *(const float4*)(gsum + c4);
  float4 qu = *(const float4*)(gsq + c4);
  float4 ga = *(const float4*)(gamma + c4);
  float4 be = *(const float4*)(beta + c4);
  float4 s, sh;
  {
    float m, v;
    m = su.x * (1.0f / NN); v = fmaxf(qu.x * (1.0f / NN) - m * m, 0.f);
    s.x = ga.x * rsqrtf(v + 1e-5f); sh.x = be.x - m * s.x;
    m = su.y * (1.0f / NN); v = fmaxf(qu.y * (1.0f / NN) - m * m, 0.f);
    s.y = ga.y * rsqrtf(v + 1e-5f); sh.y = be.y - m * s.y;
    m = su.z * (1.0f / NN); v = fmaxf(qu.z * (1.0f / NN) - m * m, 0.f);
    s.z = ga.z * rsqrtf(v + 1e-5f); sh.z = be.z - m * s.z;
    m = su.w * (1.0f / NN); v = fmaxf(qu.w * (1.0f / NN) - m * m, 0.f);
    s.w = ga.w * rsqrtf(v + 1e-5f); sh.w = be.w - m * s.w;
  }
  for (int i4 = i; i4 < total4; i4 += st) {
    float4 v = ((float4*)out)[i4];
    v.x = fmaxf(fmaf(v.x, s.x, sh.x), 0.f);
    v.y = fmaxf(fmaf(v.y, s.y, sh.y), 0.f);
    v.z = fmaxf(fmaf(v.z, s.z, sh.z), 0.f);
    v.w = fmaxf(fmaf(v.w, s.w, sh.w), 0.f);
    ((float4*)out)[i4] = v;
  }
}

extern "C" void kernel_launch(void* const* d_in, const int* in_sizes, int n_in,
                              void* d_out, int out_size, void* d_ws, size_t ws_size,
                              hipStream_t stream) {
  const float* feature = (const float*)d_in[0];
  const float* snorm   = (const float*)d_in[1];
  const int*   src     = (const int*)d_in[2];
  const int*   dst     = (const int*)d_in[3];
  const float* W       = (const float*)d_in[4];
  const float* bias    = (const float*)d_in[5];
  const float* gamma   = (const float*)d_in[6];
  const float* beta    = (const float*)d_in[7];
  float* out = (float*)d_out;

  const size_t TBL = (size_t)(NN + 1) * 64 * sizeof(u32);  // 25.6 MB + sentinel row
  char* p = (char*)d_ws;
  u32* X0b = (u32*)p; p += TBL;
  u32* Y0  = (u32*)p; p += TBL;   // reused as X2b after prop1 consumes it
  u32* X1b = (u32*)p; p += TBL;   // epair (6.4 MB) aliases this until k_fine done
  u32* X2b = Y0;
  u32* epair = (u32*)X1b;
  u32* Wf  = (u32*)p; p += 96 * 256 * sizeof(u32);   // 98.3 KB
  int* esrc = (int*)p;    p += (size_t)(EE + 8) * 4;  // padded for batch OOB reads
  int* rp   = (int*)p;    p += ((size_t)(NN + 1) * 4 + 127) & ~(size_t)127;
  float* ds = (float*)p;  p += (size_t)(NN + 1) * 4;
  int* hist_t   = (int*)p; p += (size_t)NBUCK * B1 * 4;  // 200 KB
  int* blockoff = (int*)p; p += (size_t)NBUCK * B1 * 4;  // 200 KB
  int* btot  = (int*)p;   p += 512 * 4;
  int* bbase = (int*)p;   p += 512 * 4;
  char* zbeg = p;
  float* gsum = (float*)p; p += 512;
  float* gsq  = (float*)p; p += 512;

  hipMemsetAsync(zbeg, 0, 1024, stream);  // gsum, gsq

  k_hist<<<B1, 256, 0, stream>>>(dst, hist_t);
  k_boff<<<NBUCK, B1, 0, stream>>>(hist_t, blockoff, btot);
  k_bbase<<<1, 512, 0, stream>>>(btot, bbase);
  k_bucket<<<B1, 256, 0, stream>>>(src, dst, bbase, blockoff, epair);
  k_fine<<<NBUCK, 256, 0, stream>>>(epair, bbase, rp, ds, esrc);
  k_prep<<<4096, 256, 0, stream>>>(feature, ds, X0b, Y0, X1b, W, Wf);
  k_prop1<<<NN / 4, 256, 0, stream>>>(Y0, ds, rp, esrc, X1b);
  k_prop2<<<NN / 4, 256, 0, stream>>>(X1b, X0b, ds, rp, esrc, X2b);
  k_gemm<<<(NN + 511) / 512, 1024, 0, stream>>>(X0b, X1b, X2b, Wf, bias, snorm,
                                                out, gsum, gsq);
  k_apply<<<4096, 256, 0, stream>>>(out, gsum, gsq, gamma, beta);
}